// Round 1
// 626.192 us; speedup vs baseline: 1.1410x; 1.1410x over previous
//
#include <hip/hip_runtime.h>
#include <hip/hip_bf16.h>

typedef __bf16 bf16x8 __attribute__((ext_vector_type(8)));
typedef float floatx4 __attribute__((ext_vector_type(4)));

#define AS1 __attribute__((address_space(1)))
#define AS3 __attribute__((address_space(3)))

// ---------------------------------------------------------------- cvt A fp32 -> bf16
__global__ __launch_bounds__(256) void cvt_a_kernel(const float* __restrict__ A,
                                                    __hip_bfloat16* __restrict__ Ab,
                                                    int n8) {
    int i = blockIdx.x * 256 + threadIdx.x;
    if (i >= n8) return;
    size_t base = (size_t)i * 8;
    float4 a0 = *(const float4*)(A + base);
    float4 a1 = *(const float4*)(A + base + 4);
    union { __hip_bfloat16 h[8]; float4 f; } u;
    u.h[0] = __float2bfloat16(a0.x);
    u.h[1] = __float2bfloat16(a0.y);
    u.h[2] = __float2bfloat16(a0.z);
    u.h[3] = __float2bfloat16(a0.w);
    u.h[4] = __float2bfloat16(a1.x);
    u.h[5] = __float2bfloat16(a1.y);
    u.h[6] = __float2bfloat16(a1.z);
    u.h[7] = __float2bfloat16(a1.w);
    *(float4*)(Ab + base) = u.f;
}

// ---------------------------------------------------------------- dequant B -> Wt bf16 [N][K]
// (unchanged from R3 — n-fast coalesced reads, LDS transpose, t-fast 32 B writes)
__global__ __launch_bounds__(256) void dequant_kernel(const int* __restrict__ Bp,
                                                      const float* __restrict__ s,
                                                      __hip_bfloat16* __restrict__ Wt,
                                                      int N, int T) {
    __shared__ __hip_bfloat16 tile[64][264];  // [n][t*16+r], padded stride
    const int tid = threadIdx.x;
    const int t0 = blockIdx.x * 16;
    const int n0 = blockIdx.y * 64;
    const int K = T * 16;

    {
        const int nl = tid & 63;   // n fast -> coalesced packed reads
        const int tg = tid >> 6;   // wave id = t-group
#pragma unroll
        for (int tt = 0; tt < 4; ++tt) {
            const int tl = tg * 4 + tt;
            const int t = t0 + tl;
            const int n = n0 + nl;
            const int2 p = *(const int2*)(Bp + (size_t)t * (2 * N) + 2 * n);
            const unsigned lo = (unsigned)p.x;
            const unsigned hi = (unsigned)p.y;
            const float sc = s[(size_t)(t >> 3) * N + n];  // group row = t/8
            union { __hip_bfloat16 h[16]; float4 f[2]; } u;
#pragma unroll
            for (int r = 0; r < 8; ++r) {
                u.h[r]     = __float2bfloat16(((float)((lo >> (4 * r)) & 0xFu) - 8.0f) * sc);
                u.h[r + 8] = __float2bfloat16(((float)((hi >> (4 * r)) & 0xFu) - 8.0f) * sc);
            }
            *(float4*)&tile[nl][tl * 16]     = u.f[0];
            *(float4*)&tile[nl][tl * 16 + 8] = u.f[1];
        }
    }
    __syncthreads();
    {
        const int tl = tid & 15;   // t fast -> coalesced Wt writes
        const int nq = tid >> 4;
#pragma unroll
        for (int p = 0; p < 4; ++p) {
            const int n = p * 16 + nq;
            float4 v0 = *(const float4*)&tile[n][tl * 16];
            float4 v1 = *(const float4*)&tile[n][tl * 16 + 8];
            float4* dst = (float4*)(Wt + (size_t)(n0 + n) * K + (size_t)(t0 + tl) * 16);
            dst[0] = v0;
            dst[1] = v1;
        }
    }
}

// ---------------------------------------------------------------- GEMM C = A * Wt^T + bias
// R4: port to the 256x256 8-phase counted-vmcnt structure (m194-m201).
//   - BM=BN=256, BK=64, 8 waves (2m x 4n), each wave owns 128x64 of C
//     (8x4 grid of 16x16x32 bf16 MFMA), acc = 128 VGPRs.
//   - LDS 128 KiB dynamic: 2 K-tile buffers x (A 256x64 + B 256x64) bf16.
//   - Per K-tile: 4 phases of {ds_read (af4 [+bf4]) || stage-issue ->
//     sched_barrier/s_barrier -> setprio(1) 16xMFMA setprio(0) -> barrier}.
//     bf fragments register-cached across phase pairs (4-vs-8 ds_read phases).
//   - Tile k+1 staged (8 global_load_lds/thread) in phases 1-2 of tile k into
//     the buffer freed by tile k-1 (race-free: k-1's reads completed before
//     k's phase-1 issue, by the barrier structure). vmcnt(0) waits only at
//     END of phase 4, ~2.5 phases after issue -> loads span 5 raw barriers
//     in flight (T3+T4). Raw s_barrier never drains counters (vs __syncthreads).
//   - Global-side XOR swizzle (chunk ^= row&7) kept from R2/R3: lds stays
//     linear for global_load_lds, ds_read side applies same involution ->
//     bank conflicts stay 0 (measured).
//   - XCD-bijective remap (nwg%8==0): each XCD gets 6 contiguous bx columns,
//     by-fast -> B panels (2 MB each) L2-resident per XCD.
#define GLDS(gp, lp) __builtin_amdgcn_global_load_lds((AS1 void*)(gp), (AS3 void*)(lp), 16, 0, 0)

#define STAGE_SLAB(bufsel, ss, kp)                                             \
    do {                                                                       \
        GLDS(Ast + (size_t)((ss) * 64) * K + (kp),                             \
             ldsw + (bufsel) * 32768 + (ss) * 4096);                           \
        GLDS(Bst + (size_t)((ss) * 64) * K + (kp),                             \
             ldsw + (bufsel) * 32768 + 16384 + (ss) * 4096);                   \
    } while (0)

#define PHASE(IH, KOFF, LOADB, STAGE_STMT, TAIL_STMT)                          \
    do {                                                                       \
        bf16x8 af[4];                                                          \
        _Pragma("unroll") for (int i_ = 0; i_ < 4; ++i_)                       \
            af[i_] = *(const bf16x8*)&ldsb[aBase + ((IH) * 4 + i_) * 1024 + (KOFF)]; \
        if (LOADB) {                                                           \
            _Pragma("unroll") for (int j_ = 0; j_ < 4; ++j_)                   \
                bf[j_] = *(const bf16x8*)&ldsb[bBase + j_ * 1024 + (KOFF)];    \
        }                                                                      \
        STAGE_STMT                                                             \
        __builtin_amdgcn_sched_barrier(0);                                     \
        __builtin_amdgcn_s_barrier();                                          \
        __builtin_amdgcn_sched_barrier(0);                                     \
        __builtin_amdgcn_s_setprio(1);                                         \
        _Pragma("unroll") for (int i_ = 0; i_ < 4; ++i_) {                     \
            _Pragma("unroll") for (int j_ = 0; j_ < 4; ++j_)                   \
                acc[(IH) * 4 + i_][j_] = __builtin_amdgcn_mfma_f32_16x16x32_bf16( \
                    af[i_], bf[j_], acc[(IH) * 4 + i_][j_], 0, 0, 0);          \
        }                                                                      \
        __builtin_amdgcn_s_setprio(0);                                         \
        TAIL_STMT                                                              \
        __builtin_amdgcn_sched_barrier(0);                                     \
        __builtin_amdgcn_s_barrier();                                          \
        __builtin_amdgcn_sched_barrier(0);                                     \
    } while (0)

__global__ __launch_bounds__(512, 2) void gemm256_kernel(const __hip_bfloat16* __restrict__ A,
                                                         const __hip_bfloat16* __restrict__ Bt,
                                                         const float* __restrict__ bias,
                                                         float* __restrict__ C,
                                                         int M, int N, int K) {
    extern __shared__ __hip_bfloat16 lds[];  // 65536 bf16 = 128 KiB

    const int nby = M >> 8;
    const int nbx = N >> 8;
    const int nwg = nbx * nby;
    int id = (int)blockIdx.x;
    if ((nwg & 7) == 0) {  // XCD-contiguous bijective remap
        const int cpx = nwg >> 3;
        id = (id & 7) * cpx + (id >> 3);
    }
    const int bx = id / nby;        // by-fast within bx columns
    const int by = id - bx * nby;
    const int m0 = by << 8;
    const int n0 = bx << 8;

    const int tid = (int)threadIdx.x;
    const int wave = tid >> 6;
    const int lane = tid & 63;
    const int wm = wave >> 2;  // 0..1
    const int wn = wave & 3;   // 0..3

    // staging: wave covers 8 rows x 128 B per slab-issue; global src pre-swizzled
    const int srow = (wave << 3) + (lane >> 3);                 // 0..63 in slab
    const int scol = ((lane & 7) ^ ((lane >> 3) & 7)) << 3;     // chunk ^ (row&7)
    const __hip_bfloat16* Ast = A + (size_t)(m0 + srow) * K + scol;
    const __hip_bfloat16* Bst = Bt + (size_t)(n0 + srow) * K + scol;
    __hip_bfloat16* const ldsw = lds + (wave << 9);             // wave-uniform dst

    // ds_read bases: row*64 elems; chunk t read at t ^ (row&7)
    const int aBase = (wm * 128 + (lane & 15)) * 64;
    const int bBase = 16384 + (wn * 64 + (lane & 15)) * 64;
    const int koff0 = ((lane >> 4) ^ (lane & 7)) * 8;           // ks=0 chunks
    const int koff1 = ((4 + (lane >> 4)) ^ (lane & 7)) * 8;     // ks=1 chunks

    floatx4 acc[8][4];
#pragma unroll
    for (int i = 0; i < 8; ++i)
#pragma unroll
        for (int j = 0; j < 4; ++j) acc[i][j] = (floatx4){0.f, 0.f, 0.f, 0.f};

    // prologue: stage tile 0 into buffer 0, drain, join
#pragma unroll
    for (int ss = 0; ss < 4; ++ss) STAGE_SLAB(0, ss, 0);
    asm volatile("s_waitcnt vmcnt(0)" ::: "memory");
    __builtin_amdgcn_sched_barrier(0);
    __builtin_amdgcn_s_barrier();
    __builtin_amdgcn_sched_barrier(0);

    const int nkt = K >> 6;
    for (int kt = 0; kt < nkt; ++kt) {
        const __hip_bfloat16* ldsb = lds + (kt & 1) * 32768;
        const int bufp = (kt & 1) ^ 1;
        const int kp = (kt + 1) << 6;
        const bool pf = (kt + 1) < nkt;
        bf16x8 bf[4];
        PHASE(0, koff0, 1,
              { if (pf) { STAGE_SLAB(bufp, 0, kp); STAGE_SLAB(bufp, 1, kp); } },
              {});
        PHASE(1, koff0, 0,
              { if (pf) { STAGE_SLAB(bufp, 2, kp); STAGE_SLAB(bufp, 3, kp); } },
              {});
        PHASE(0, koff1, 1, {}, {});
        PHASE(1, koff1, 0, {},
              { asm volatile("s_waitcnt vmcnt(0)" ::: "memory"); });
    }

    // epilogue: C/D layout col=lane&15, row=(lane>>4)*4+reg  [m89-verified]
    const int cl = lane & 15;
    const int rq = (lane >> 4) << 2;
#pragma unroll
    for (int j = 0; j < 4; ++j) {
        const int n = n0 + wn * 64 + j * 16 + cl;
        const float bv = bias[n];
#pragma unroll
        for (int i = 0; i < 8; ++i) {
            const int mb = m0 + wm * 128 + i * 16 + rq;
#pragma unroll
            for (int r = 0; r < 4; ++r) {
                float v = acc[i][j][r] + bv;
                __builtin_nontemporal_store(v, &C[(size_t)(mb + r) * N + n]);
            }
        }
    }
}

// ---------------------------------------------------------------- launch
extern "C" void kernel_launch(void* const* d_in, const int* in_sizes, int n_in,
                              void* d_out, int out_size, void* d_ws, size_t ws_size,
                              hipStream_t stream) {
    const float* A = (const float*)d_in[0];
    const int* Bp = (const int*)d_in[1];
    const float* s = (const float*)d_in[2];
    const float* bias = (const float*)d_in[3];
    float* C = (float*)d_out;

    const int N = in_sizes[3];                        // 12288
    const long Bsz = (long)in_sizes[1];               // (K/16)*(2N)
    const int K = (int)(Bsz / (2L * N)) * 16;         // 4096
    const int M = (int)((long)in_sizes[0] / K);       // 4096
    const int T = K / 16;

    __hip_bfloat16* Ab = (__hip_bfloat16*)d_ws;                               // M*K*2 B
    __hip_bfloat16* Wt = (__hip_bfloat16*)((char*)d_ws + (size_t)M * K * 2);  // N*K*2 B

    // 128 KiB dynamic LDS opt-in (host-side attr set, not a stream op -> capture-safe)
    static int attr_done = 0;
    if (!attr_done) {
        (void)hipFuncSetAttribute((const void*)gemm256_kernel,
                                  hipFuncAttributeMaxDynamicSharedMemorySize, 131072);
        attr_done = 1;
    }

    const int n8 = (M * K) / 8;
    cvt_a_kernel<<<(n8 + 255) / 256, 256, 0, stream>>>(A, Ab, n8);
    dequant_kernel<<<dim3(T / 16, N / 64), 256, 0, stream>>>(Bp, s, Wt, N, T);
    const int nwg = (M >> 8) * (N >> 8);              // 768, %8==0
    gemm256_kernel<<<nwg, 512, 131072, stream>>>(Ab, Wt, bias, C, M, N, K);
}

// Round 2
// 621.579 us; speedup vs baseline: 1.1495x; 1.0074x over previous
//
#include <hip/hip_runtime.h>
#include <hip/hip_bf16.h>

typedef __bf16 bf16x8 __attribute__((ext_vector_type(8)));
typedef float floatx4 __attribute__((ext_vector_type(4)));

#define AS1 __attribute__((address_space(1)))
#define AS3 __attribute__((address_space(3)))

// ---------------------------------------------------------------- fused prep:
// blocks [0, ncvt)        : cvt A fp32 -> bf16 (8 elems/thread)
// blocks [ncvt, ncvt+ndq) : dequant B int4 -> Wt bf16 [N][K]
// Fusing lets the two independent memory streams overlap and saves a launch gap.
__global__ __launch_bounds__(256) void prep_kernel(const float* __restrict__ A,
                                                   __hip_bfloat16* __restrict__ Ab, int n8,
                                                   const int* __restrict__ Bp,
                                                   const float* __restrict__ s,
                                                   __hip_bfloat16* __restrict__ Wt,
                                                   int N, int T, int ncvt) {
    __shared__ __hip_bfloat16 tile[64][264];  // dequant LDS transpose buffer
    if ((int)blockIdx.x < ncvt) {
        int i = blockIdx.x * 256 + threadIdx.x;
        if (i >= n8) return;
        size_t base = (size_t)i * 8;
        float4 a0 = *(const float4*)(A + base);
        float4 a1 = *(const float4*)(A + base + 4);
        union { __hip_bfloat16 h[8]; float4 f; } u;
        u.h[0] = __float2bfloat16(a0.x);
        u.h[1] = __float2bfloat16(a0.y);
        u.h[2] = __float2bfloat16(a0.z);
        u.h[3] = __float2bfloat16(a0.w);
        u.h[4] = __float2bfloat16(a1.x);
        u.h[5] = __float2bfloat16(a1.y);
        u.h[6] = __float2bfloat16(a1.z);
        u.h[7] = __float2bfloat16(a1.w);
        *(float4*)(Ab + base) = u.f;
        return;
    }
    // ---- dequant part (R3 logic, flat-indexed)
    const int d = (int)blockIdx.x - ncvt;
    const int nbt = T / 16;
    const int t0 = (d % nbt) * 16;
    const int n0 = (d / nbt) * 64;
    const int tid = threadIdx.x;
    const int K = T * 16;
    {
        const int nl = tid & 63;   // n fast -> coalesced packed reads
        const int tg = tid >> 6;   // wave id = t-group
#pragma unroll
        for (int tt = 0; tt < 4; ++tt) {
            const int tl = tg * 4 + tt;
            const int t = t0 + tl;
            const int n = n0 + nl;
            const int2 p = *(const int2*)(Bp + (size_t)t * (2 * N) + 2 * n);
            const unsigned lo = (unsigned)p.x;
            const unsigned hi = (unsigned)p.y;
            const float sc = s[(size_t)(t >> 3) * N + n];  // group row = t/8
            union { __hip_bfloat16 h[16]; float4 f[2]; } u;
#pragma unroll
            for (int r = 0; r < 8; ++r) {
                u.h[r]     = __float2bfloat16(((float)((lo >> (4 * r)) & 0xFu) - 8.0f) * sc);
                u.h[r + 8] = __float2bfloat16(((float)((hi >> (4 * r)) & 0xFu) - 8.0f) * sc);
            }
            *(float4*)&tile[nl][tl * 16]     = u.f[0];
            *(float4*)&tile[nl][tl * 16 + 8] = u.f[1];
        }
    }
    __syncthreads();
    {
        const int tl = tid & 15;   // t fast -> coalesced Wt writes
        const int nq = tid >> 4;
#pragma unroll
        for (int p = 0; p < 4; ++p) {
            const int n = p * 16 + nq;
            float4 v0 = *(const float4*)&tile[n][tl * 16];
            float4 v1 = *(const float4*)&tile[n][tl * 16 + 8];
            float4* dst = (float4*)(Wt + (size_t)(n0 + n) * K + (size_t)(t0 + tl) * 16);
            dst[0] = v0;
            dst[1] = v1;
        }
    }
}

// ---------------------------------------------------------------- GEMM C = A * Wt^T + bias
// R5: depth-3 counted-vmcnt pipeline (T4). BK 64->32, LDS = 4 buffers x
// (A 256x32 + B 256x32) bf16 = 128 KiB. Tile t+3's 4 GLDS issue during tile t;
// end-of-tile wait = vmcnt(8) (t+2,t+3 stay in flight; t+1 forced complete).
// Issue-to-wait distance ~5-6 phases (~1000 cyc) >= HBM latency; odd tiles'
// staging hits L2 (other half of the 128-B line). Tail peeled vmcnt(4)/(0).
// LDS swizzle for 64-B rows: granule (r,c) lives at chunk-slot c ^ ((r>>1)&3);
// any 8 consecutive lanes of ds_read_b128 hit 8 distinct 16-B slots (2-way max
// over wave64 = free). Staging inverse is linear in lane ((l>>2)*64+(l&3)*16 =
// l*16) so global_load_lds dest stays wave-uniform-base + lane*16.
#define GLDS(gp, lp) __builtin_amdgcn_global_load_lds((AS1 void*)(gp), (AS3 void*)(lp), 16, 0, 0)

// stage round rd (rows rd*128..rd*128+127) of tile tt into buffer tt&3
#define STAGE_TILE_RD(tt, rd)                                                  \
    do {                                                                       \
        const int bp_ = (tt) & 3;                                              \
        const size_t kg_ = (size_t)(tt) * 32 + (size_t)(rd) * 128 * K;         \
        GLDS(Astg + kg_, lds + bp_ * 16384 + (rd) * 4096 + ldst);              \
        GLDS(Bstg + kg_, lds + bp_ * 16384 + 8192 + (rd) * 4096 + ldst);       \
    } while (0)

#define TILE(tt, PF, WAIT_STMT)                                                \
    do {                                                                       \
        const __hip_bfloat16* ldsb = lds + ((tt) & 3) * 16384;                 \
        bf16x8 bf[4];                                                          \
        { /* phase 0: rows 0..63 of wave's half + all B quads */               \
            bf16x8 af[4];                                                      \
            _Pragma("unroll") for (int i_ = 0; i_ < 4; ++i_)                   \
                af[i_] = *(const bf16x8*)&ldsb[aoff + i_ * 512];               \
            _Pragma("unroll") for (int j_ = 0; j_ < 4; ++j_)                   \
                bf[j_] = *(const bf16x8*)&ldsb[boff + j_ * 512];               \
            if (PF) STAGE_TILE_RD((tt) + 3, 0);                                \
            __builtin_amdgcn_sched_barrier(0);                                 \
            __builtin_amdgcn_s_barrier();                                      \
            __builtin_amdgcn_sched_barrier(0);                                 \
            __builtin_amdgcn_s_setprio(1);                                     \
            _Pragma("unroll") for (int i_ = 0; i_ < 4; ++i_) {                 \
                _Pragma("unroll") for (int j_ = 0; j_ < 4; ++j_)               \
                    acc[i_][j_] = __builtin_amdgcn_mfma_f32_16x16x32_bf16(     \
                        af[i_], bf[j_], acc[i_][j_], 0, 0, 0);                 \
            }                                                                  \
            __builtin_amdgcn_s_setprio(0);                                     \
            __builtin_amdgcn_sched_barrier(0);                                 \
            __builtin_amdgcn_s_barrier();                                      \
            __builtin_amdgcn_sched_barrier(0);                                 \
        }                                                                      \
        { /* phase 1: rows 64..127 of wave's half, reuse bf */                 \
            bf16x8 af[4];                                                      \
            _Pragma("unroll") for (int i_ = 0; i_ < 4; ++i_)                   \
                af[i_] = *(const bf16x8*)&ldsb[aoff + 2048 + i_ * 512];        \
            if (PF) STAGE_TILE_RD((tt) + 3, 1);                                \
            __builtin_amdgcn_sched_barrier(0);                                 \
            __builtin_amdgcn_s_barrier();                                      \
            __builtin_amdgcn_sched_barrier(0);                                 \
            __builtin_amdgcn_s_setprio(1);                                     \
            _Pragma("unroll") for (int i_ = 0; i_ < 4; ++i_) {                 \
                _Pragma("unroll") for (int j_ = 0; j_ < 4; ++j_)               \
                    acc[4 + i_][j_] = __builtin_amdgcn_mfma_f32_16x16x32_bf16( \
                        af[i_], bf[j_], acc[4 + i_][j_], 0, 0, 0);             \
            }                                                                  \
            __builtin_amdgcn_s_setprio(0);                                     \
            WAIT_STMT;                                                         \
            __builtin_amdgcn_sched_barrier(0);                                 \
            __builtin_amdgcn_s_barrier();                                      \
            __builtin_amdgcn_sched_barrier(0);                                 \
        }                                                                      \
    } while (0)

__global__ __launch_bounds__(512, 2) void gemm256_kernel(const __hip_bfloat16* __restrict__ A,
                                                         const __hip_bfloat16* __restrict__ Bt,
                                                         const float* __restrict__ bias,
                                                         float* __restrict__ C,
                                                         int M, int N, int K) {
    extern __shared__ __hip_bfloat16 lds[];  // 65536 elems = 128 KiB: 4 x (A 8192 | B 8192)

    const int nby = M >> 8;
    const int nbx = N >> 8;
    const int nwg = nbx * nby;
    int id = (int)blockIdx.x;
    if ((nwg & 7) == 0) {  // XCD-contiguous bijective remap
        const int cpx = nwg >> 3;
        id = (id & 7) * cpx + (id >> 3);
    }
    const int bx = id / nby;        // by-fast within bx columns
    const int by = id - bx * nby;
    const int m0 = by << 8;
    const int n0 = bx << 8;

    const int tid = (int)threadIdx.x;
    const int wave = tid >> 6;
    const int lane = tid & 63;
    const int wm = wave >> 2;  // 0..1
    const int wn = wave & 3;   // 0..3
    const int ln = lane & 15;
    const int qd = lane >> 4;              // k-chunk quad
    const int sw = (ln >> 1) & 3;          // read-side slot key ((row>>1)&3)

    // staging: wave covers 16 rows x 64 B (4 chunks); source pre-swizzled so
    // linear LDS dest == swizzled granule home.
    const int srow = (wave << 4) + (lane >> 2);               // 0..127 (round 0)
    const int schunk = (lane & 3) ^ ((lane >> 3) & 3);
    const __hip_bfloat16* Astg = A + (size_t)(m0 + srow) * K + schunk * 8;
    const __hip_bfloat16* Bstg = Bt + (size_t)(n0 + srow) * K + schunk * 8;
    const int ldst = (wave << 9);          // wave-uniform LDS dst offset (elems)

    // ds_read bases (elems): row*32 + (chunk ^ slotkey)*8
    const int aoff = (wm * 128 + ln) * 32 + ((qd ^ sw) << 3);
    const int boff = 8192 + (wn * 64 + ln) * 32 + ((qd ^ sw) << 3);

    floatx4 acc[8][4];
#pragma unroll
    for (int i = 0; i < 8; ++i)
#pragma unroll
        for (int j = 0; j < 4; ++j) acc[i][j] = (floatx4){0.f, 0.f, 0.f, 0.f};

    const int nkt = K >> 5;  // BK=32 tiles

    // prologue: stage tiles 0,1,2 (12 loads); force tile 0 complete (vmcnt 8)
    STAGE_TILE_RD(0, 0); STAGE_TILE_RD(0, 1);
    STAGE_TILE_RD(1, 0); STAGE_TILE_RD(1, 1);
    STAGE_TILE_RD(2, 0); STAGE_TILE_RD(2, 1);
    asm volatile("s_waitcnt vmcnt(8)" ::: "memory");
    __builtin_amdgcn_sched_barrier(0);
    __builtin_amdgcn_s_barrier();
    __builtin_amdgcn_sched_barrier(0);

    int t = 0;
    for (; t + 3 < nkt; ++t)
        TILE(t, 1, asm volatile("s_waitcnt vmcnt(8)" ::: "memory"));
    // tail: no more issues; tighten waits so each next tile is guaranteed staged
    TILE(t, 0, asm volatile("s_waitcnt vmcnt(4)" ::: "memory")); ++t;
    TILE(t, 0, asm volatile("s_waitcnt vmcnt(0)" ::: "memory")); ++t;
    TILE(t, 0, ((void)0));

    // epilogue: C/D layout col=lane&15, row=(lane>>4)*4+reg  [m89-verified]
    const int cl = lane & 15;
    const int rq = (lane >> 4) << 2;
#pragma unroll
    for (int j = 0; j < 4; ++j) {
        const int n = n0 + wn * 64 + j * 16 + cl;
        const float bv = bias[n];
#pragma unroll
        for (int i = 0; i < 8; ++i) {
            const int mb = m0 + wm * 128 + i * 16 + rq;
#pragma unroll
            for (int r = 0; r < 4; ++r) {
                float v = acc[i][j][r] + bv;
                __builtin_nontemporal_store(v, &C[(size_t)(mb + r) * N + n]);
            }
        }
    }
}

// ---------------------------------------------------------------- launch
extern "C" void kernel_launch(void* const* d_in, const int* in_sizes, int n_in,
                              void* d_out, int out_size, void* d_ws, size_t ws_size,
                              hipStream_t stream) {
    const float* A = (const float*)d_in[0];
    const int* Bp = (const int*)d_in[1];
    const float* s = (const float*)d_in[2];
    const float* bias = (const float*)d_in[3];
    float* C = (float*)d_out;

    const int N = in_sizes[3];                        // 12288
    const long Bsz = (long)in_sizes[1];               // (K/16)*(2N)
    const int K = (int)(Bsz / (2L * N)) * 16;         // 4096
    const int M = (int)((long)in_sizes[0] / K);       // 4096
    const int T = K / 16;

    __hip_bfloat16* Ab = (__hip_bfloat16*)d_ws;                               // M*K*2 B
    __hip_bfloat16* Wt = (__hip_bfloat16*)((char*)d_ws + (size_t)M * K * 2);  // N*K*2 B

    // 128 KiB dynamic LDS opt-in (host-side attr set, capture-safe)
    static int attr_done = 0;
    if (!attr_done) {
        (void)hipFuncSetAttribute((const void*)gemm256_kernel,
                                  hipFuncAttributeMaxDynamicSharedMemorySize, 131072);
        attr_done = 1;
    }

    const int n8 = (M * K) / 8;
    const int ncvt = (n8 + 255) / 256;                // 8192
    const int ndq = (T / 16) * (N / 64);              // 3072
    prep_kernel<<<ncvt + ndq, 256, 0, stream>>>(A, Ab, n8, Bp, s, Wt, N, T, ncvt);
    const int nwg = (M >> 8) * (N >> 8);              // 768, %8==0
    gemm256_kernel<<<nwg, 512, 131072, stream>>>(Ab, Wt, bias, C, M, N, K);
}

// Round 3
// 616.767 us; speedup vs baseline: 1.1584x; 1.0078x over previous
//
#include <hip/hip_runtime.h>
#include <hip/hip_bf16.h>

typedef __bf16 bf16x8 __attribute__((ext_vector_type(8)));
typedef float floatx4 __attribute__((ext_vector_type(4)));

#define AS1 __attribute__((address_space(1)))
#define AS3 __attribute__((address_space(3)))

// ---------------------------------------------------------------- fused prep:
// blocks [0, ncvt)        : cvt A fp32 -> bf16 (8 elems/thread)
// blocks [ncvt, ncvt+ndq) : dequant B int4 -> Wt bf16 [N][K]
__global__ __launch_bounds__(256) void prep_kernel(const float* __restrict__ A,
                                                   __hip_bfloat16* __restrict__ Ab, int n8,
                                                   const int* __restrict__ Bp,
                                                   const float* __restrict__ s,
                                                   __hip_bfloat16* __restrict__ Wt,
                                                   int N, int T, int ncvt) {
    __shared__ __hip_bfloat16 tile[64][264];  // dequant LDS transpose buffer
    if ((int)blockIdx.x < ncvt) {
        int i = blockIdx.x * 256 + threadIdx.x;
        if (i >= n8) return;
        size_t base = (size_t)i * 8;
        float4 a0 = *(const float4*)(A + base);
        float4 a1 = *(const float4*)(A + base + 4);
        union { __hip_bfloat16 h[8]; float4 f; } u;
        u.h[0] = __float2bfloat16(a0.x);
        u.h[1] = __float2bfloat16(a0.y);
        u.h[2] = __float2bfloat16(a0.z);
        u.h[3] = __float2bfloat16(a0.w);
        u.h[4] = __float2bfloat16(a1.x);
        u.h[5] = __float2bfloat16(a1.y);
        u.h[6] = __float2bfloat16(a1.z);
        u.h[7] = __float2bfloat16(a1.w);
        *(float4*)(Ab + base) = u.f;
        return;
    }
    const int d = (int)blockIdx.x - ncvt;
    const int nbt = T / 16;
    const int t0 = (d % nbt) * 16;
    const int n0 = (d / nbt) * 64;
    const int tid = threadIdx.x;
    const int K = T * 16;
    {
        const int nl = tid & 63;   // n fast -> coalesced packed reads
        const int tg = tid >> 6;   // wave id = t-group
#pragma unroll
        for (int tt = 0; tt < 4; ++tt) {
            const int tl = tg * 4 + tt;
            const int t = t0 + tl;
            const int n = n0 + nl;
            const int2 p = *(const int2*)(Bp + (size_t)t * (2 * N) + 2 * n);
            const unsigned lo = (unsigned)p.x;
            const unsigned hi = (unsigned)p.y;
            const float sc = s[(size_t)(t >> 3) * N + n];  // group row = t/8
            union { __hip_bfloat16 h[16]; float4 f[2]; } u;
#pragma unroll
            for (int r = 0; r < 8; ++r) {
                u.h[r]     = __float2bfloat16(((float)((lo >> (4 * r)) & 0xFu) - 8.0f) * sc);
                u.h[r + 8] = __float2bfloat16(((float)((hi >> (4 * r)) & 0xFu) - 8.0f) * sc);
            }
            *(float4*)&tile[nl][tl * 16]     = u.f[0];
            *(float4*)&tile[nl][tl * 16 + 8] = u.f[1];
        }
    }
    __syncthreads();
    {
        const int tl = tid & 15;   // t fast -> coalesced Wt writes
        const int nq = tid >> 4;
#pragma unroll
        for (int p = 0; p < 4; ++p) {
            const int n = p * 16 + nq;
            float4 v0 = *(const float4*)&tile[n][tl * 16];
            float4 v1 = *(const float4*)&tile[n][tl * 16 + 8];
            float4* dst = (float4*)(Wt + (size_t)(n0 + n) * K + (size_t)(t0 + tl) * 16);
            dst[0] = v0;
            dst[1] = v1;
        }
    }
}

// ---------------------------------------------------------------- GEMM C = A * Wt^T + bias
// R6: register-level fragment double-buffer (phase-ahead ds_reads).
// R5 post-mortem: counted vmcnt depth-3 was neutral -> vmcnt wasn't the stall;
// the ~120cyc ds_read latency was serially exposed each phase (read just
// before barrier, consumed just after). Now every fragment is read ONE PHASE
// ahead of its MFMA cluster:
//   P0(t): [reads afB = P1 frags of t] then MFMA(afA x bfC) ; stage rd0(t+3);
//          vmcnt(6) (forces t+1 staged -> P1 may read t+1's buffer); barrier.
//   P1(t): [reads afA = P0 frags of t+1, bfN = B of t+1] then MFMA(afB x bfC);
//          stage rd1(t+3); barrier.
// Compiler emits counted lgkmcnt automatically (waits only consumed set,
// leaves prefetch in flight) - no inline lgkm asm (rule #18 avoided).
// sched_group_barrier(DS_READ,n) pins reads at region top so regalloc can't
// sink them below MFMA. B frags ping-pong per tile, A frags per phase; 2-tile
// unrolled main loop keeps all indices static (rule #20). 4 LDS buffers: next
// writer of any buffer being read is >=2 tiles away (WAR safe).
#define GLDS(gp, lp) __builtin_amdgcn_global_load_lds((AS1 void*)(gp), (AS3 void*)(lp), 16, 0, 0)

#define STAGE_TILE_RD(tt, rd)                                                  \
    do {                                                                       \
        const int bp_ = (tt) & 3;                                              \
        const size_t kg_ = (size_t)(tt) * 32 + (size_t)(rd) * 128 * K;         \
        GLDS(Astg + kg_, lds + bp_ * 16384 + (rd) * 4096 + ldst);              \
        GLDS(Bstg + kg_, lds + bp_ * 16384 + 8192 + (rd) * 4096 + ldst);       \
    } while (0)

#define MFMA_(a, b, c) __builtin_amdgcn_mfma_f32_16x16x32_bf16((a), (b), (c), 0, 0, 0)
#define SGB_DSREAD(n) __builtin_amdgcn_sched_group_barrier(0x100, (n), 0)
#define FENCE_BAR()                                                            \
    do {                                                                       \
        __builtin_amdgcn_sched_barrier(0);                                     \
        __builtin_amdgcn_s_barrier();                                          \
        __builtin_amdgcn_sched_barrier(0);                                     \
    } while (0)
#define VM6 asm volatile("s_waitcnt vmcnt(6)" ::: "memory")
#define VM4 asm volatile("s_waitcnt vmcnt(4)" ::: "memory")
#define VM0 asm volatile("s_waitcnt vmcnt(0)" ::: "memory")
#define VMN ((void)0)

// AF0: frags for P0 of tile tt (already arriving; issued last P1)
// AF1: filled during P0, used by P1
// BFC: B frags of tile tt (in regs), BFN: B frags of tt+1 (filled in P1)
#define TILE_GEN(tt, AF0, AF1, BFC, BFN, PF, VWAIT, NEXTRD)                    \
    do {                                                                       \
        const __hip_bfloat16* ldsb_ = lds + ((tt) & 3) * 16384;                \
        const __hip_bfloat16* ldsn_ = lds + (((tt) + 1) & 3) * 16384;          \
        /* ---- P0 ---- */                                                     \
        SGB_DSREAD(4);                                                         \
        _Pragma("unroll") for (int i_ = 0; i_ < 4; ++i_)                       \
            AF1[i_] = *(const bf16x8*)&ldsb_[aoff + 2048 + i_ * 512];          \
        __builtin_amdgcn_s_setprio(1);                                         \
        _Pragma("unroll") for (int i_ = 0; i_ < 4; ++i_) {                     \
            _Pragma("unroll") for (int j_ = 0; j_ < 4; ++j_)                   \
                acc[i_][j_] = MFMA_(AF0[i_], BFC[j_], acc[i_][j_]);            \
        }                                                                      \
        __builtin_amdgcn_s_setprio(0);                                         \
        if (PF) STAGE_TILE_RD((tt) + 3, 0);                                    \
        VWAIT;                                                                 \
        FENCE_BAR();                                                           \
        /* ---- P1 ---- */                                                     \
        if (NEXTRD) {                                                          \
            SGB_DSREAD(8);                                                     \
            _Pragma("unroll") for (int i_ = 0; i_ < 4; ++i_)                   \
                AF0[i_] = *(const bf16x8*)&ldsn_[aoff + i_ * 512];             \
            _Pragma("unroll") for (int j_ = 0; j_ < 4; ++j_)                   \
                BFN[j_] = *(const bf16x8*)&ldsn_[boff + j_ * 512];             \
        }                                                                      \
        __builtin_amdgcn_s_setprio(1);                                         \
        _Pragma("unroll") for (int i_ = 0; i_ < 4; ++i_) {                     \
            _Pragma("unroll") for (int j_ = 0; j_ < 4; ++j_)                   \
                acc[4 + i_][j_] = MFMA_(AF1[i_], BFC[j_], acc[4 + i_][j_]);    \
        }                                                                      \
        __builtin_amdgcn_s_setprio(0);                                         \
        if (PF) STAGE_TILE_RD((tt) + 3, 1);                                    \
        FENCE_BAR();                                                           \
    } while (0)

__global__ __launch_bounds__(512, 2) void gemm256_kernel(const __hip_bfloat16* __restrict__ A,
                                                         const __hip_bfloat16* __restrict__ Bt,
                                                         const float* __restrict__ bias,
                                                         float* __restrict__ C,
                                                         int M, int N, int K) {
    extern __shared__ __hip_bfloat16 lds[];  // 65536 elems = 128 KiB: 4 x (A 8192 | B 8192)

    const int nby = M >> 8;
    const int nbx = N >> 8;
    const int nwg = nbx * nby;
    int id = (int)blockIdx.x;
    if ((nwg & 7) == 0) {  // XCD-contiguous bijective remap
        const int cpx = nwg >> 3;
        id = (id & 7) * cpx + (id >> 3);
    }
    const int bx = id / nby;        // by-fast within bx columns
    const int by = id - bx * nby;
    const int m0 = by << 8;
    const int n0 = bx << 8;

    const int tid = (int)threadIdx.x;
    const int wave = tid >> 6;
    const int lane = tid & 63;
    const int wm = wave >> 2;  // 0..1
    const int wn = wave & 3;   // 0..3
    const int ln = lane & 15;
    const int qd = lane >> 4;              // k-chunk quad
    const int sw = (ln >> 1) & 3;          // read-side slot key ((row>>1)&3)

    // staging: wave covers 16 rows x 64 B (4 chunks); source pre-swizzled so
    // linear LDS dest == swizzled granule home. slot = chunk ^ ((row>>1)&3).
    const int srow = (wave << 4) + (lane >> 2);               // 0..127 (round 0)
    const int schunk = (lane & 3) ^ ((lane >> 3) & 3);
    const __hip_bfloat16* Astg = A + (size_t)(m0 + srow) * K + schunk * 8;
    const __hip_bfloat16* Bstg = Bt + (size_t)(n0 + srow) * K + schunk * 8;
    const int ldst = (wave << 9);          // wave-uniform LDS dst offset (elems)

    // ds_read bases (elems): row*32 + (chunk ^ slotkey)*8
    const int aoff = (wm * 128 + ln) * 32 + ((qd ^ sw) << 3);
    const int boff = 8192 + (wn * 64 + ln) * 32 + ((qd ^ sw) << 3);

    floatx4 acc[8][4];
#pragma unroll
    for (int i = 0; i < 8; ++i)
#pragma unroll
        for (int j = 0; j < 4; ++j) acc[i][j] = (floatx4){0.f, 0.f, 0.f, 0.f};

    const int nkt = K >> 5;  // BK=32 tiles (assume even, K % 64 == 0)

    // prologue: stage tiles 0,1,2; force tile 0 complete; pre-read tile 0 frags
    STAGE_TILE_RD(0, 0); STAGE_TILE_RD(0, 1);
    STAGE_TILE_RD(1, 0); STAGE_TILE_RD(1, 1);
    STAGE_TILE_RD(2, 0); STAGE_TILE_RD(2, 1);
    asm volatile("s_waitcnt vmcnt(8)" ::: "memory");
    FENCE_BAR();

    bf16x8 afA[4], afB[4], bfA[4], bfB[4];
#pragma unroll
    for (int i = 0; i < 4; ++i) afA[i] = *(const bf16x8*)&lds[aoff + i * 512];
#pragma unroll
    for (int j = 0; j < 4; ++j) bfA[j] = *(const bf16x8*)&lds[boff + j * 512];

    int t = 0;
    for (; t + 4 < nkt; t += 2) {
        TILE_GEN(t,     afA, afB, bfA, bfB, 1, VM6, 1);
        TILE_GEN(t + 1, afA, afB, bfB, bfA, 1, VM6, 1);
    }
    // tail: tiles nkt-4 .. nkt-1 (parities even/odd/even/odd since nkt even)
    TILE_GEN(t,     afA, afB, bfA, bfB, 1, VM6, 1); ++t;   // stages nkt-1
    TILE_GEN(t,     afA, afB, bfB, bfA, 0, VM4, 1); ++t;
    TILE_GEN(t,     afA, afB, bfA, bfB, 0, VM0, 1); ++t;
    TILE_GEN(t,     afA, afB, bfB, bfA, 0, VMN, 0);

    // epilogue: C/D layout col=lane&15, row=(lane>>4)*4+reg  [m89-verified]
    const int cl = lane & 15;
    const int rq = (lane >> 4) << 2;
#pragma unroll
    for (int j = 0; j < 4; ++j) {
        const int n = n0 + wn * 64 + j * 16 + cl;
        const float bv = bias[n];
#pragma unroll
        for (int i = 0; i < 8; ++i) {
            const int mb = m0 + wm * 128 + i * 16 + rq;
#pragma unroll
            for (int r = 0; r < 4; ++r) {
                float v = acc[i][j][r] + bv;
                __builtin_nontemporal_store(v, &C[(size_t)(mb + r) * N + n]);
            }
        }
    }
}

// ---------------------------------------------------------------- launch
extern "C" void kernel_launch(void* const* d_in, const int* in_sizes, int n_in,
                              void* d_out, int out_size, void* d_ws, size_t ws_size,
                              hipStream_t stream) {
    const float* A = (const float*)d_in[0];
    const int* Bp = (const int*)d_in[1];
    const float* s = (const float*)d_in[2];
    const float* bias = (const float*)d_in[3];
    float* C = (float*)d_out;

    const int N = in_sizes[3];                        // 12288
    const long Bsz = (long)in_sizes[1];               // (K/16)*(2N)
    const int K = (int)(Bsz / (2L * N)) * 16;         // 4096
    const int M = (int)((long)in_sizes[0] / K);       // 4096
    const int T = K / 16;

    __hip_bfloat16* Ab = (__hip_bfloat16*)d_ws;                               // M*K*2 B
    __hip_bfloat16* Wt = (__hip_bfloat16*)((char*)d_ws + (size_t)M * K * 2);  // N*K*2 B

    // 128 KiB dynamic LDS opt-in (host-side attr set, capture-safe)
    static int attr_done = 0;
    if (!attr_done) {
        (void)hipFuncSetAttribute((const void*)gemm256_kernel,
                                  hipFuncAttributeMaxDynamicSharedMemorySize, 131072);
        attr_done = 1;
    }

    const int n8 = (M * K) / 8;
    const int ncvt = (n8 + 255) / 256;                // 8192
    const int ndq = (T / 16) * (N / 64);              // 3072
    prep_kernel<<<ncvt + ndq, 256, 0, stream>>>(A, Ab, n8, Bp, s, Wt, N, T, ncvt);
    const int nwg = (M >> 8) * (N >> 8);              // 768, %8==0
    gemm256_kernel<<<nwg, 512, 131072, stream>>>(Ab, Wt, bias, C, M, N, K);
}